// Round 9
// baseline (510.332 us; speedup 1.0000x reference)
//
#include <hip/hip_runtime.h>

#define HB 32
#define HT 256
#define HC 2048
#define HH 16
#define HD 128
#define HM (HB * HT)  // 8192

typedef __bf16 bf16x8 __attribute__((ext_vector_type(8)));
typedef float f32x4 __attribute__((ext_vector_type(4)));

__device__ __forceinline__ unsigned short f2bf(float f) {
  unsigned u = __float_as_uint(f);
  u += 0x7FFFu + ((u >> 16) & 1u);  // round-to-nearest-even
  return (unsigned short)(u >> 16);
}

// ---------------- fused fp32 -> bf16 convert (x + 4 weights) ----------------
__global__ __launch_bounds__(256) void cvt_all(
    const float* __restrict__ x, const float* __restrict__ wq, const float* __restrict__ wk,
    const float* __restrict__ wv, const float* __restrict__ wo,
    unsigned short* __restrict__ xb, unsigned short* __restrict__ wqb,
    unsigned short* __restrict__ wkb, unsigned short* __restrict__ wvb,
    unsigned short* __restrict__ wob) {
  size_t i = (size_t)blockIdx.x * 256 + threadIdx.x;
  const float* src;
  unsigned short* dst;
  size_t off;
  if (i < 4194304) {
    src = x; dst = xb; off = i;
  } else {
    size_t j = i - 4194304;
    int w = (int)(j >> 20);
    off = j & 1048575;
    src = (w == 0) ? wq : (w == 1) ? wk : (w == 2) ? wv : wo;
    dst = (w == 0) ? wqb : (w == 1) ? wkb : (w == 2) ? wvb : wob;
  }
  float4 v = ((const float4*)src)[off];
  ushort4 o;
  o.x = f2bf(v.x); o.y = f2bf(v.y); o.z = f2bf(v.z); o.w = f2bf(v.w);
  ((ushort4*)dst)[off] = o;
}

// ---------------- GEMM core: 256x256 tile, BK=32, 4-deep ring, 2 phases/tile ----
// Round-9: round-2's pipelined schedule (T3 fine interleave + T4 counted vmcnt +
// T5 setprio; passed correctness at 545us) x round-3's verified conflict-free
// swizzle. Round 2's slot^(row&3) at 64B pitch collapses to 2 slot values on
// same-parity rows -> 4-way conflict (measured 2.5e7); (row>>1)&3 covers all 4
// slots over the 8 same-parity lanes -> 2-way = free (round-3: measured 0).
// T2 gates T3 (dependency graph): this is the previously-untested quadrant.
__device__ __forceinline__ void gl_lds16(const unsigned short* g, unsigned short* l) {
  __builtin_amdgcn_global_load_lds((const __attribute__((address_space(1))) void*)g,
                                   (__attribute__((address_space(3))) void*)l, 16, 0, 0);
}

// wave wn owns col-blocks {h*128 + s, +16, +64+s, +80} with s=32*(wn&1), h=wn>>1:
// frag pair (nf, nf+2) is (d, d+64) of one head -> RoPE pair stays in-lane.
__device__ __forceinline__ int nfcol(int wn, int nf) {
  return (wn >> 1) * 128 + (wn & 1) * 32 + (nf & 1) * 16 + (nf >> 1) * 64;
}

// Stage one 256x32 bf16 tile (16 KB) = 2 x 16B loads/thread. LDS dest linear
// (chunk c at byte c*16, wave-uniform base + lane*16); source column pre-swizzled
// gc = slot ^ ((row>>1)&3) (m173 both-sides pattern; round-3-verified parity).
__device__ __forceinline__ void stage32(const unsigned short* __restrict__ src,
                                        unsigned short* dst, int tid) {
#pragma unroll
  for (int i = 0; i < 2; i++) {
    int c = i * 512 + tid;
    int row = c >> 2, slot = c & 3;
    int gc = slot ^ ((row >> 1) & 3);
    gl_lds16(src + (size_t)row * HC + gc * 8, dst + c * 8);
  }
}

#define KT 64  // K=2048 / BK=32

__device__ __forceinline__ void gemm_core8(const unsigned short* __restrict__ A,
                                           const unsigned short* __restrict__ W,
                                           unsigned short* lsA, unsigned short* lsB,
                                           f32x4 acc[8][4], int tid) {
  const int lane = tid & 63, l16 = lane & 15, quad = lane >> 4;
  const int wave = tid >> 6, wm = wave >> 2, wn = wave & 3;
  // fragment rows are 16-aligned + l16 -> (row>>1)&3 == (l16>>1)&3, lane-constant
  const int ch8 = (quad ^ ((l16 >> 1) & 3)) * 8;

  // prologue: stage tiles 0,1,2 (12 loads); vmcnt(8) -> tile 0 landed, 1-2 in flight
  stage32(A, lsA, tid);
  stage32(W, lsB, tid);
  stage32(A + 32, lsA + 8192, tid);
  stage32(W + 32, lsB + 8192, tid);
  stage32(A + 64, lsA + 16384, tid);
  stage32(W + 64, lsB + 16384, tid);
  asm volatile("s_waitcnt vmcnt(8)");
  __builtin_amdgcn_s_barrier();

  for (int t = 0; t < KT; ++t) {
    const unsigned short* cA = lsA + (t & 3) * 8192;
    const unsigned short* cB = lsB + (t & 3) * 8192;
    unsigned short* nA = lsA + ((t + 3) & 3) * 8192;  // buffer of t-1: freed at its ph1 barrier-2
    unsigned short* nB = lsB + ((t + 3) & 3) * 8192;
    const bool pf = (t + 3 < KT);
#pragma unroll
    for (int ph = 0; ph < 2; ++ph) {
      // --- 8 x ds_read_b128: one output quadrant's fragments ---
      bf16x8 af[4], bfv[4];
#pragma unroll
      for (int mf = 0; mf < 4; ++mf) {
        int row = wm * 128 + ph * 64 + mf * 16 + l16;
        af[mf] = *(const bf16x8*)(cA + row * 32 + ch8);
      }
#pragma unroll
      for (int nf = 0; nf < 4; ++nf) {
        int row = nfcol(wn, nf) + l16;
        bfv[nf] = *(const bf16x8*)(cB + row * 32 + ch8);
      }
      // --- issue 1 half-tile prefetch for tile t+3 ---
      if (pf) {
        if (ph == 0) stage32(A + (size_t)(t + 3) * 32, nA, tid);
        else         stage32(W + (size_t)(t + 3) * 32, nB, tid);
      }
      // --- counted vmcnt once per K-tile, BEFORE a barrier (publishes tile t+1
      //     cross-wave). Steady state keeps 8 loads (t+2,t+3) in flight. ---
      if (ph == 1) {
        const int rem = KT - 2 - t;
        if (rem >= 2)      asm volatile("s_waitcnt vmcnt(8)");
        else if (rem == 1) asm volatile("s_waitcnt vmcnt(4)");
        else if (rem == 0) asm volatile("s_waitcnt vmcnt(0)");
      }
      __builtin_amdgcn_s_barrier();
      __builtin_amdgcn_s_setprio(1);
#pragma unroll
      for (int mf = 0; mf < 4; ++mf)
#pragma unroll
        for (int nf = 0; nf < 4; ++nf)
          acc[ph * 4 + mf][nf] =
              __builtin_amdgcn_mfma_f32_16x16x32_bf16(af[mf], bfv[nf], acc[ph * 4 + mf][nf], 0, 0, 0);
      __builtin_amdgcn_s_setprio(0);
      __builtin_amdgcn_s_barrier();
    }
  }
}

// Output projection GEMM: fp32 out [M, 2048]; grid (32, 8)
__global__ __launch_bounds__(512, 2) void gemm_out(const unsigned short* __restrict__ A,
                                                   const unsigned short* __restrict__ W,
                                                   float* __restrict__ outp) {
  __shared__ __align__(16) unsigned short lsA[32768];
  __shared__ __align__(16) unsigned short lsB[32768];
  const int tid = threadIdx.x;
  const int lane = tid & 63, wave = tid >> 6;
  const int l16 = lane & 15, quad = lane >> 4;
  const int wm = wave >> 2, wn = wave & 3;
  const int bm = blockIdx.x, bn = blockIdx.y;

  f32x4 acc[8][4];
#pragma unroll
  for (int i = 0; i < 8; i++)
#pragma unroll
    for (int j = 0; j < 4; j++) acc[i][j] = f32x4{0.f, 0.f, 0.f, 0.f};

  gemm_core8(A + (size_t)bm * 256 * HC, W + (size_t)bn * 256 * HC, lsA, lsB, acc, tid);

#pragma unroll
  for (int mf = 0; mf < 8; mf++)
#pragma unroll
    for (int nf = 0; nf < 4; nf++) {
      const int n = bn * 256 + nfcol(wn, nf) + l16;
#pragma unroll
      for (int r = 0; r < 4; r++) {
        const int m = bm * 256 + wm * 128 + mf * 16 + quad * 4 + r;
        outp[(size_t)m * HC + n] = acc[mf][nf][r];
      }
    }
}

// Fused QKV GEMM: grid (32, 24); blockIdx.y>>3 selects {Q,K,V}.
// Q,K -> [B,H,T,D] with RoPE fused; V -> [B,H,D,T] via operand swap (coalesced).
__global__ __launch_bounds__(512, 2) void gemm_qkv(const unsigned short* __restrict__ A,
                                                   const unsigned short* __restrict__ W0,
                                                   const unsigned short* __restrict__ W1,
                                                   const unsigned short* __restrict__ W2,
                                                   unsigned short* __restrict__ Qo,
                                                   unsigned short* __restrict__ Ko,
                                                   unsigned short* __restrict__ Vto) {
  __shared__ __align__(16) unsigned short lsA[32768];
  __shared__ __align__(16) unsigned short lsB[32768];
  const int tid = threadIdx.x;
  const int lane = tid & 63, wave = tid >> 6;
  const int l16 = lane & 15, quad = lane >> 4;
  const int wm = wave >> 2, wn = wave & 3;
  const int bm = blockIdx.x;
  const int which = blockIdx.y >> 3;
  const int bn = blockIdx.y & 7;

  f32x4 acc[8][4];
#pragma unroll
  for (int i = 0; i < 8; i++)
#pragma unroll
    for (int j = 0; j < 4; j++) acc[i][j] = f32x4{0.f, 0.f, 0.f, 0.f};

  if (which < 2) {
    const unsigned short* W = (which == 0) ? W0 : W1;
    unsigned short* outp = (which == 0) ? Qo : Ko;
    gemm_core8(A + (size_t)bm * 256 * HC, W + (size_t)bn * 256 * HC, lsA, lsB, acc, tid);
    // wave covers head h = bn*2 + (wn>>1); frag pair (p, p+2) = (d, d+64) in-lane.
    const int h = bn * 2 + (wn >> 1);
#pragma unroll
    for (int p = 0; p < 2; p++) {
      const int d = (wn & 1) * 32 + p * 16 + l16;  // [0,64)
      const float invf = __expf((float)d * (-0.14391156831212787f));
#pragma unroll
      for (int mf = 0; mf < 8; mf++)
#pragma unroll
        for (int r = 0; r < 4; r++) {
          const int m = bm * 256 + wm * 128 + mf * 16 + quad * 4 + r;
          const int t = m & 255, b = m >> 8;
          float ang = (float)t * invf;
          float sn, cs;
          __sincosf(ang, &sn, &cs);
          float lo = acc[mf][p][r], hi = acc[mf][p + 2][r];
          size_t base = (((size_t)b * HH + h) * HT + t) * HD;
          outp[base + d] = f2bf(lo * cs - hi * sn);
          outp[base + 64 + d] = f2bf(hi * cs + lo * sn);
        }
    }
  } else {
    // V^T: A-operand = wv channel tile (256 ch = 2 heads), B-operand = x token tile (256 = 1 batch).
    const int tok = bm;  // 0..31
    const int ch = bn;   // 0..7
    gemm_core8(W2 + (size_t)ch * 256 * HC, A + (size_t)tok * 256 * HC, lsA, lsB, acc, tid);
#pragma unroll
    for (int mf = 0; mf < 8; mf++)
#pragma unroll
      for (int nf = 0; nf < 4; nf++) {
        const int tcol = nfcol(wn, nf) + l16;
#pragma unroll
        for (int r = 0; r < 4; r++) {
          const int cabs = ch * 256 + wm * 128 + mf * 16 + quad * 4 + r;
          const int hh = cabs >> 7, d = cabs & 127;
          Vto[(((size_t)tok * HH + hh) * HD + d) * HT + tcol] = f2bf(acc[mf][nf][r]);
        }
      }
  }
}

// ---------------- causal flash attention ----------------
// Round-8 body (K-load batching confirmed ~+18us after chip-noise normalization).
// Pairing {3,0}/{2,1} + T13 defer-max + ks=0 V-hoist + kf[4][2] batch retained.
__global__ __launch_bounds__(256) void attn_kernel(const unsigned short* __restrict__ Q,
                                                   const unsigned short* __restrict__ K,
                                                   const unsigned short* __restrict__ Vt,
                                                   unsigned short* __restrict__ Y) {
  const int g = blockIdx.x;      // 1024 blocks
  const int bh = g & 511;
  const int pairp = g >> 9;      // 0 -> {3,0}, 1 -> {2,1}
  const int wave = threadIdx.x >> 6;
  const int lane = threadIdx.x & 63;
  const int quad = lane >> 4, l16 = lane & 15;

  const unsigned short* Qh = Q + (size_t)bh * HT * HD;
  const unsigned short* Kh = K + (size_t)bh * HT * HD;
  const unsigned short* Vh = Vt + (size_t)bh * HD * HT;

  __shared__ __align__(16) unsigned short P[4][16 * 72];
  unsigned short* Pw = P[wave];

  const float scale = 0.088388347648318447f;  // 1/sqrt(128)
  const int b = bh >> 4, h = bh & 15;

  for (int half = 0; half < 2; ++half) {
    const int wq = (pairp == 0) ? (half == 0 ? 3 : 0) : (half == 0 ? 2 : 1);
    const int qrow = wq * 64 + wave * 16;

    bf16x8 qf[4];
#pragma unroll
    for (int ks = 0; ks < 4; ks++)
      qf[ks] = *(const bf16x8*)(Qh + (size_t)(qrow + l16) * HD + ks * 32 + quad * 8);

    f32x4 o[8];
#pragma unroll
    for (int di = 0; di < 8; di++) o[di] = f32x4{0.f, 0.f, 0.f, 0.f};
    float mrow[4], lrow[4];
#pragma unroll
    for (int r = 0; r < 4; r++) { mrow[r] = -1e30f; lrow[r] = 0.f; }

    for (int ct = 0; ct <= wq; ++ct) {
      f32x4 s[4];
#pragma unroll
      for (int ni = 0; ni < 4; ni++) s[ni] = f32x4{0.f, 0.f, 0.f, 0.f};
      const int nimax = (ct == wq) ? wave : 3;
      // QK^T in two half-K batches: issue 8 independent K loads, then 8 MFMAs.
#pragma unroll
      for (int ksh = 0; ksh < 2; ksh++) {
        bf16x8 kf[4][2];
#pragma unroll
        for (int ni = 0; ni < 4; ni++)
          if (ni <= nimax)
#pragma unroll
            for (int k2 = 0; k2 < 2; k2++)
              kf[ni][k2] = *(const bf16x8*)(Kh + (size_t)(ct * 64 + ni * 16 + l16) * HD +
                                            (ksh * 2 + k2) * 32 + quad * 8);
#pragma unroll
        for (int k2 = 0; k2 < 2; k2++)
#pragma unroll
          for (int ni = 0; ni < 4; ni++)
            if (ni <= nimax)
              s[ni] = __builtin_amdgcn_mfma_f32_16x16x32_bf16(qf[ksh * 2 + k2], kf[ni][k2],
                                                              s[ni], 0, 0, 0);
      }
      // T14 hoist: issue ks=0 half of the V tile now; latency hides under softmax.
      bf16x8 vf0[8];
#pragma unroll
      for (int di = 0; di < 8; di++)
        vf0[di] = *(const bf16x8*)(Vh + (size_t)(di * 16 + l16) * HT + ct * 64 + quad * 8);

      if (ct == wq) {
#pragma unroll
        for (int ni = 0; ni < 4; ni++)
#pragma unroll
          for (int r = 0; r < 4; r++) {
            int qr = wave * 16 + quad * 4 + r;
            int kc = ni * 16 + l16;
            s[ni][r] = (kc <= qr) ? s[ni][r] * scale : -1e30f;
          }
      } else {
#pragma unroll
        for (int ni = 0; ni < 4; ni++)
#pragma unroll
          for (int r = 0; r < 4; r++) s[ni][r] *= scale;
      }
      // per-row max (uniform within 16-lane group)
      float pm[4];
#pragma unroll
      for (int r = 0; r < 4; r++) {
        float v = fmaxf(fmaxf(s[0][r], s[1][r]), fmaxf(s[2][r], s[3][r]));
        v = fmaxf(v, __shfl_xor(v, 1, 64));
        v = fmaxf(v, __shfl_xor(v, 2, 64));
        v = fmaxf(v, __shfl_xor(v, 4, 64));
        v = fmaxf(v, __shfl_xor(v, 8, 64));
        pm[r] = v;
      }
      // T13 defer-max: wave-uniform rescale test (max growth across all 16 rows)
      float ex = fmaxf(fmaxf(pm[0] - mrow[0], pm[1] - mrow[1]),
                       fmaxf(pm[2] - mrow[2], pm[3] - mrow[3]));
      ex = fmaxf(ex, __shfl_xor(ex, 16, 64));
      ex = fmaxf(ex, __shfl_xor(ex, 32, 64));
      if (ex > 8.f) {
#pragma unroll
        for (int r = 0; r < 4; r++) {
          float mnew = fmaxf(mrow[r], pm[r]);
          float alpha = __expf(mrow[r] - mnew);
          mrow[r] = mnew;
          lrow[r] *= alpha;
#pragma unroll
          for (int di = 0; di < 8; di++) o[di][r] *= alpha;
        }
      }
#pragma unroll
      for (int r = 0; r < 4; r++) {
        float rs = 0.f;
#pragma unroll
        for (int ni = 0; ni < 4; ni++) {
          float e = __expf(s[ni][r] - mrow[r]);
          s[ni][r] = e;
          rs += e;
        }
        rs += __shfl_xor(rs, 1, 64);
        rs += __shfl_xor(rs, 2, 64);
        rs += __shfl_xor(rs, 4, 64);
        rs += __shfl_xor(rs, 8, 64);
        lrow[r] += rs;
      }
#pragma unroll
      for (int ni = 0; ni < 4; ni++)
#pragma unroll
        for (int r = 0; r < 4; r++)
          Pw[(quad * 4 + r) * 72 + ni * 16 + l16] = f2bf(s[ni][r]);
      // PV: ks=0 uses the hoisted vf0; ks=1 loads inline.
      {
        bf16x8 pf = *(const bf16x8*)(Pw + (size_t)l16 * 72 + quad * 8);
#pragma unroll
        for (int di = 0; di < 8; di++)
          o[di] = __builtin_amdgcn_mfma_f32_16x16x32_bf16(pf, vf0[di], o[di], 0, 0, 0);
      }
      {
        bf16x8 pf = *(const bf16x8*)(Pw + (size_t)l16 * 72 + 32 + quad * 8);
#pragma unroll
        for (int di = 0; di < 8; di++) {
          bf16x8 vf = *(const bf16x8*)(Vh + (size_t)(di * 16 + l16) * HT + ct * 64 + 32 + quad * 8);
          o[di] = __builtin_amdgcn_mfma_f32_16x16x32_bf16(pf, vf, o[di], 0, 0, 0);
        }
      }
    }

#pragma unroll
    for (int r = 0; r < 4; r++) {
      float inv = 1.f / lrow[r];
      int t = qrow + quad * 4 + r;
      size_t rowb = ((size_t)b * HT + t) * HC + h * HD;
#pragma unroll
      for (int di = 0; di < 8; di++)
        Y[rowb + di * 16 + l16] = f2bf(o[di][r] * inv);
    }
  }
}

// ---------------- launch ----------------
extern "C" void kernel_launch(void* const* d_in, const int* in_sizes, int n_in,
                              void* d_out, int out_size, void* d_ws, size_t ws_size,
                              hipStream_t stream) {
  const float* x  = (const float*)d_in[0];
  const float* wq = (const float*)d_in[1];
  const float* wk = (const float*)d_in[2];
  const float* wv = (const float*)d_in[3];
  const float* wo = (const float*)d_in[4];
  float* out = (float*)d_out;

  char* ws = (char*)d_ws;
  const size_t MB = (size_t)1 << 20;
  unsigned short* wqb = (unsigned short*)(ws + 0 * MB);
  unsigned short* wkb = (unsigned short*)(ws + 8 * MB);
  unsigned short* wvb = (unsigned short*)(ws + 16 * MB);
  unsigned short* wob = (unsigned short*)(ws + 24 * MB);
  unsigned short* xb  = (unsigned short*)(ws + 32 * MB);
  unsigned short* Qb  = (unsigned short*)(ws + 64 * MB);
  unsigned short* Kb  = (unsigned short*)(ws + 96 * MB);
  unsigned short* Vtb = (unsigned short*)(ws + 128 * MB);
  unsigned short* Yb  = xb;  // reuse x's bf16 buffer after QKV GEMMs

  cvt_all<<<32768, 256, 0, stream>>>(x, wq, wk, wv, wo, xb, wqb, wkb, wvb, wob);

  gemm_qkv<<<dim3(HM / 256, 24), 512, 0, stream>>>(xb, wqb, wkb, wvb, Qb, Kb, Vtb);

  attn_kernel<<<1024, 256, 0, stream>>>(Qb, Kb, Vtb, Yb);

  gemm_out<<<dim3(HM / 256, HC / 256), 512, 0, stream>>>(Yb, wob, out);
}